// Round 5
// baseline (244.654 us; speedup 1.0000x reference)
//
#include <hip/hip_runtime.h>

#define NB 4            // batches
#define NA 120000       // anchors
#define NC 80           // classes
#define NM 32           // annotations per batch

#define EPS_   1e-4f
#define LN2_   0.69314718055994531f

constexpr int MBLOCK = 192;                // meta kernel: 3 waves; 120000 = 625 * 192
constexpr int SBLOCK = 256;                // stream kernel: 4 waves
constexpr int APB    = 64;                 // anchors per stream block; 256*5 float4 = 64*20
constexpr int U      = 5;                  // float4 per thread in stream kernel
constexpr int BINS   = 64;                 // atomic spreading bins per (batch, quantity)
// d_ws layout:
//   acc:  double[NB*3*BINS]  at offset 0      (6144 B)   q: 0=cls, 1=reg, 2=pos
//   coef: float[NB*NA]       at offset 8192   (1.92 MB)

__device__ __forceinline__ float wave_reduce_f(float v) {
    #pragma unroll
    for (int off = 32; off > 0; off >>= 1) v += __shfl_down(v, off, 64);
    return v;
}
__device__ __forceinline__ double wave_reduce_d(double v) {
    #pragma unroll
    for (int off = 32; off > 0; off >>= 1) v += __shfl_down(v, off, 64);
    return v;
}

// fast log2 -> v_log_f32 (inputs are clamped well away from denormals)
__device__ __forceinline__ float flog2(float x) { return __builtin_amdgcn_logf(x); }

// ---------------- Kernel A: per-anchor meta (IoU, pos corrections, reg loss) -------
__global__ __launch_bounds__(MBLOCK)
void focal_meta(const float* __restrict__ cls,
                const float* __restrict__ reg,
                const float* __restrict__ anchors,
                const float* __restrict__ ann,
                float* __restrict__ coef,
                double* __restrict__ acc)
{
    __shared__ float s_ann[NM * 10];
    __shared__ float s_red[3][3];

    const int b   = blockIdx.y;
    const int tid = threadIdx.x;
    const int a   = blockIdx.x * MBLOCK + tid;   // exact: 625*192 = 120000

    const float* annB = ann + b * NM * 10;
    s_ann[tid] = annB[tid];
    if (tid < NM * 10 - MBLOCK) s_ann[MBLOCK + tid] = annB[MBLOCK + tid];
    __syncthreads();

    float regLoss = 0.0f, posCnt = 0.0f, clsCorr = 0.0f;
    {
        const float4 an = ((const float4*)anchors)[a];
        const float ax1 = an.x, ay1 = an.y, ax2 = an.z, ay2 = an.w;
        const float aw  = ax2 - ax1, ah = ay2 - ay1;
        const float acx = ax1 + 0.5f * aw, acy = ay1 + 0.5f * ah;
        const float areaA = aw * ah;

        float best = -1.0f;
        int   arg  = 0;
        #pragma unroll
        for (int m = 0; m < NM; ++m) {
            const float bx1 = s_ann[m * 10 + 4];
            const float by1 = s_ann[m * 10 + 5];
            const float bx2 = s_ann[m * 10 + 6];
            const float by2 = s_ann[m * 10 + 7];
            float iw = fminf(ax2, bx2) - fmaxf(ax1, bx1); iw = fmaxf(iw, 0.0f);
            float ih = fminf(ay2, by2) - fmaxf(ay1, by1); ih = fmaxf(ih, 0.0f);
            const float inter = iw * ih;
            const float areaB = (bx2 - bx1) * (by2 - by1);
            const float ua    = fmaxf(areaA + areaB - inter, 1e-8f);
            const float iou   = inter / ua;
            if (iou > best) { best = iou; arg = m; }   // first-max (jnp.argmax)
        }

        const bool pos = best >= 0.5f;
        const bool neg = best < 0.4f;
        // per-anchor coefficient for the uniform neg-term sweep (0 for ignore)
        coef[(size_t)b * NA + a] = (pos || neg) ? (-0.25f * LN2_) : 0.0f;

        if (pos) {
            posCnt = 1.0f;
            const int c = (int)s_ann[arg * 10 + 8];
            // correction: replace neg-term with pos-term at the assigned class
            const float xc = cls[((size_t)b * NA + a) * NC + c];
            const float p  = fminf(fmaxf(xc, EPS_), 1.0f - EPS_);
            const float q  = 1.0f - p;
            const float posT = 0.75f * q * q * (-LN2_ * flog2(p));
            const float negT = 0.25f * p * p * (-LN2_ * flog2(q));
            clsCorr = posT - negT;

            // regression loss: only components 0..3 (full box) survive the mask
            const float fx1 = s_ann[arg * 10 + 4];
            const float fy1 = s_ann[arg * 10 + 5];
            const float fx2 = s_ann[arg * 10 + 6];
            const float fy2 = s_ann[arg * 10 + 7];
            float gw = fx2 - fx1, gh = fy2 - fy1;
            const float gcx = fx1 + 0.5f * gw, gcy = fy1 + 0.5f * gh; // pre-clip centers
            gw = fmaxf(gw, 1.0f); gh = fmaxf(gh, 1.0f);
            const float t0 = ((gcx - acx) / aw) * 10.0f;
            const float t1 = ((gcy - acy) / ah) * 10.0f;
            const float t2 = (LN2_ * flog2(gw / aw)) * 5.0f;
            const float t3 = (LN2_ * flog2(gh / ah)) * 5.0f;
            const float4 r4 = ((const float4*)reg)[(size_t)(b * NA + a) * 2];
            const float d0 = fabsf(t0 - r4.x);
            const float d1 = fabsf(t1 - r4.y);
            const float d2 = fabsf(t2 - r4.z);
            const float d3 = fabsf(t3 - r4.w);
            const float beta = 1.0f / 9.0f;
            #define SL1(d) ((d) <= beta ? 4.5f * (d) * (d) : (d) - 0.5f / 9.0f)
            regLoss = SL1(d0) + SL1(d1) + SL1(d2) + SL1(d3);
            #undef SL1
        }
    }

    const int wave = tid >> 6, lane = tid & 63;
    float rc = wave_reduce_f(clsCorr);
    float rr = wave_reduce_f(regLoss);
    float rp = wave_reduce_f(posCnt);
    if (lane == 0) { s_red[0][wave] = rc; s_red[1][wave] = rr; s_red[2][wave] = rp; }
    __syncthreads();
    if (tid == 0) {
        const float c = s_red[0][0] + s_red[0][1] + s_red[0][2];
        const float r = s_red[1][0] + s_red[1][1] + s_red[1][2];
        const float p = s_red[2][0] + s_red[2][1] + s_red[2][2];
        const int bin = blockIdx.x & (BINS - 1);
        atomicAdd(&acc[(b * 3 + 0) * BINS + bin], (double)c);
        atomicAdd(&acc[(b * 3 + 1) * BINS + bin], (double)r);
        atomicAdd(&acc[(b * 3 + 2) * BINS + bin], (double)p);
    }
}

// ---------------- Kernel B: pure streaming neg-term sweep --------------------------
__global__ __launch_bounds__(SBLOCK)
void focal_stream(const float* __restrict__ cls,
                  const float* __restrict__ coef,
                  double* __restrict__ acc)
{
    __shared__ float s_coef[APB];
    __shared__ float s_red[4];

    const int b   = blockIdx.y;
    const int a0  = blockIdx.x * APB;
    const int tid = threadIdx.x;

    // barrier guards only this 256 B coalesced load — all waves stream immediately
    if (tid < APB) s_coef[tid] = coef[(size_t)b * NA + a0 + tid];
    __syncthreads();

    const float4* base4 = (const float4*)(cls + (size_t)b * NA * NC) + (size_t)a0 * (NC / 4);

    float4 x[U];
    #pragma unroll
    for (int j = 0; j < U; ++j)
        x[j] = base4[j * SBLOCK + tid];

    float clsSum = 0.0f;
    #pragma unroll
    for (int j = 0; j < U; ++j) {
        const int idx = j * SBLOCK + tid;          // 0..1279
        const float C = s_coef[idx / (NC / 4)];
        const float4 x4 = x[j];

        float p0 = fminf(fmaxf(x4.x, EPS_), 1.0f - EPS_);
        float p1 = fminf(fmaxf(x4.y, EPS_), 1.0f - EPS_);
        float p2 = fminf(fmaxf(x4.z, EPS_), 1.0f - EPS_);
        float p3 = fminf(fmaxf(x4.w, EPS_), 1.0f - EPS_);

        float t0 = p0 * p0 * flog2(1.0f - p0);
        float t1 = p1 * p1 * flog2(1.0f - p1);
        float t2 = p2 * p2 * flog2(1.0f - p2);
        float t3 = p3 * p3 * flog2(1.0f - p3);

        clsSum = fmaf((t0 + t1) + (t2 + t3), C, clsSum);
    }

    const int wave = tid >> 6, lane = tid & 63;
    float rc = wave_reduce_f(clsSum);
    if (lane == 0) s_red[wave] = rc;
    __syncthreads();
    if (tid == 0) {
        const float c = (s_red[0] + s_red[1]) + (s_red[2] + s_red[3]);
        const int bin = blockIdx.x & (BINS - 1);
        atomicAdd(&acc[(b * 3 + 0) * BINS + bin], (double)c);
    }
}

__global__ void focal_finalize(const double* __restrict__ acc, float* __restrict__ out) {
    __shared__ double g[NB * 3];
    const int tid  = threadIdx.x;          // 768 threads = 12 waves, one per (b,q)
    const int wave = tid >> 6, lane = tid & 63;
    double v = acc[wave * BINS + lane];
    v = wave_reduce_d(v);
    if (lane == 0) g[wave] = v;
    __syncthreads();
    if (tid == 0) {
        double clsTot = 0.0, regTot = 0.0;
        #pragma unroll
        for (int b = 0; b < NB; ++b) {
            const double np  = g[b * 3 + 2];
            const double npc = np < 1.0 ? 1.0 : np;
            clsTot += g[b * 3 + 0] / npc;
            regTot += (np > 0.0) ? g[b * 3 + 1] / (npc * 4.0) : 0.0;
        }
        out[0] = (float)(clsTot / NB);
        out[1] = (float)(regTot / NB);
    }
}

extern "C" void kernel_launch(void* const* d_in, const int* in_sizes, int n_in,
                              void* d_out, int out_size, void* d_ws, size_t ws_size,
                              hipStream_t stream) {
    const float* cls     = (const float*)d_in[0];   // (B, A, C)
    const float* reg     = (const float*)d_in[1];   // (B, A, 8)
    const float* anchors = (const float*)d_in[2];   // (1, A, 4)
    const float* ann     = (const float*)d_in[3];   // (B, M, 10)
    float* out  = (float*)d_out;
    double* acc = (double*)d_ws;                                   // 768 doubles
    float* coef = (float*)((char*)d_ws + 8192);                    // NB*NA floats

    hipMemsetAsync(acc, 0, NB * 3 * BINS * sizeof(double), stream);

    dim3 gridA(NA / MBLOCK, NB);                    // (625, 4)
    focal_meta<<<gridA, MBLOCK, 0, stream>>>(cls, reg, anchors, ann, coef, acc);

    dim3 gridB(NA / APB, NB);                       // (1875, 4)
    focal_stream<<<gridB, SBLOCK, 0, stream>>>(cls, coef, acc);

    focal_finalize<<<1, NB * 3 * BINS, 0, stream>>>(acc, out);
}